// Round 1
// 631.955 us; speedup vs baseline: 1.1653x; 1.1653x over previous
//
#include <hip/hip_runtime.h>
#include <hip/hip_bf16.h>

#define B_ 2
#define S_ 4096
#define HID_ 2048
#define NH_ 32
#define NKV_ 8
#define HD_ 64
#define GROUPS_ 4
#define NCH_ 32   // outer_sum S-chunks

typedef short short8 __attribute__((ext_vector_type(8)));
typedef float floatx4 __attribute__((ext_vector_type(4)));

__device__ __forceinline__ float bf2f(unsigned short u){
  union { unsigned int i; float f; } v; v.i = ((unsigned int)u) << 16; return v.f;
}
__device__ __forceinline__ unsigned short f2bf(float f){
  union { float f; unsigned int i; } v; v.f = f;
  unsigned int i = v.i;
  unsigned int r = (i + 0x7fffu + ((i >> 16) & 1u)) >> 16;  // RNE
  return (unsigned short)r;
}

// async global->LDS, 16B per lane, LDS dest = wave-uniform base + lane*16
__device__ __forceinline__ void async_copy16(unsigned short* lds, const unsigned short* g){
  __builtin_amdgcn_global_load_lds((const __attribute__((address_space(1))) void*)g,
                                   (__attribute__((address_space(3))) void*)lds,
                                   16, 0, 0);
}

// ---------------- fp32 -> bf16 bulk convert (hidden_states) ----------------
__global__ void conv_bf16(const float* __restrict__ x, unsigned short* __restrict__ y, int n4){
  int i = blockIdx.x * 256 + threadIdx.x;
  if (i < n4){
    float4 v = ((const float4*)x)[i];
    ushort4 o;
    o.x = f2bf(v.x); o.y = f2bf(v.y); o.z = f2bf(v.z); o.w = f2bf(v.w);
    ((ushort4*)y)[i] = o;
  }
}

// ---------------- W[K,N] fp32 -> Wt[N,K] bf16 (tiled transpose) ----------------
__global__ void transpose_to_bf16(const float* __restrict__ W, unsigned short* __restrict__ Wt,
                                  int K, int N){
  __shared__ float tile[32][33];
  int n0 = blockIdx.x * 32, k0 = blockIdx.y * 32;
  int tx = threadIdx.x, ty = threadIdx.y;   // 32 x 8
  #pragma unroll
  for (int j = 0; j < 4; j++)
    tile[ty + j*8][tx] = W[(size_t)(k0 + ty + j*8) * N + n0 + tx];
  __syncthreads();
  #pragma unroll
  for (int j = 0; j < 4; j++)
    Wt[(size_t)(n0 + ty + j*8) * K + k0 + tx] = f2bf(tile[tx][ty + j*8]);
}

// ---------------- 256x256-tile 8-phase GEMM: C[M,N] fp32 = A[M,K] bf16 @ Bt[N,K]^T ----------------
// 512 threads = 8 waves (2 M x 4 N), per-wave 128x64 output (8x4 mfma_16x16x32 frags).
// BK=64, double-buffered 128 KiB LDS. 4 phases per K-tile:
//   p0: read A m0-3 + B n0-1 (12 ds_read_b128)          | MFMA m0-3 x n0-1
//   p1: read A m4-7 + B n2-3 (12)                       | MFMA m0-3 x n2-3
//   p2: stage A halves of tile T+2 into current buf     | MFMA m4-7 x n0-1
//   p3: stage B halves of tile T+2; s_waitcnt vmcnt(8)  | MFMA m4-7 x n2-3
// Counted vmcnt(8) keeps tile T+2's 8 loads in flight across barriers (never drains
// in the main loop). LDS XOR swizzle: 16B slot s = chunk ^ (row&7), applied on the
// pre-swizzled GLOBAL source (linear global_load_lds dest) and on the ds_read offset.
#define GTILE 16384   // 256*64 bf16 elements per operand per buffer

__global__ __launch_bounds__(512, 2) void gemm256(
    const unsigned short* __restrict__ A, const unsigned short* __restrict__ Bt,
    float* __restrict__ C, int M, int N, int K)
{
  __shared__ __align__(16) unsigned short As[2 * GTILE];
  __shared__ __align__(16) unsigned short Bs[2 * GTILE];

  const int tid = threadIdx.x;
  const int w = tid >> 6, lane = tid & 63;
  const int wr = w >> 2, wc = w & 3;
  const int l15 = lane & 15, quad = lane >> 4;

  // bijective XCD-aware swizzle (nwg % 8 == 0 for all shapes here)
  const int nbx = N >> 8;
  int flat = blockIdx.y * nbx + blockIdx.x;
  int nwg  = nbx * (M >> 8);
  int cpx  = nwg >> 3;
  int swz  = (flat & 7) * cpx + (flat >> 3);
  int bx = swz % nbx, by = swz / nbx;
  const int m0 = by << 8, n0 = bx << 8;

  // ---- staging addressing (per wave-call: 64 lanes x 16B = 512 shorts linear in LDS) ----
  const int srow = (w << 3) + (lane >> 3);          // row 0..63 within a 64-row call
  const int scc  = (lane & 7) ^ (lane >> 3);        // swizzled 16B chunk within 128B row
  const unsigned short* gA = A  + (size_t)(m0 + srow) * K + scc * 8;
  const unsigned short* gB = Bt + (size_t)(n0 + srow) * K + scc * 8;
  const size_t rs64  = (size_t)64  * K;             // second-call row offset
  const size_t rs128 = (size_t)128 * K;             // half-tile row offset
  unsigned short* lA0 = As + (w << 9);
  unsigned short* lB0 = Bs + (w << 9);

#define STAGE_A(bsel, h, t) do { \
    unsigned short* _d = lA0 + (bsel) * GTILE + (h) * 8192; \
    const unsigned short* _g = gA + (size_t)(h) * rs128 + (size_t)(t) * 64; \
    async_copy16(_d, _g); \
    async_copy16(_d + 4096, _g + rs64); \
  } while (0)
#define STAGE_B(bsel, h, t) do { \
    unsigned short* _d = lB0 + (bsel) * GTILE + (h) * 8192; \
    const unsigned short* _g = gB + (size_t)(h) * rs128 + (size_t)(t) * 64; \
    async_copy16(_d, _g); \
    async_copy16(_d + 4096, _g + rs64); \
  } while (0)
#define SCHED0 __builtin_amdgcn_sched_barrier(0)

  // ---- fragment read offsets (shorts): row*64 + ((kchunk ^ (row&7))<<3); row&7 == lane&7 ----
  const int ks0  = ((quad     ^ (lane & 7)) << 3);
  const int ks1  = (((4+quad) ^ (lane & 7)) << 3);
  const int arow = (wr * 128 + l15) * 64;
  const int brow = (wc * 64  + l15) * 64;

  floatx4 acc[8][4] = {};
  short8 af[8][2], bfr[4][2];

  const int nt = K >> 6;

  // ---- prologue: stage tile0 (buf0) and tile1 (buf1); allow tile1's 8 loads in flight ----
  STAGE_A(0, 0, 0); STAGE_A(0, 1, 0); STAGE_B(0, 0, 0); STAGE_B(0, 1, 0);
  if (nt > 1){
    STAGE_A(1, 0, 1); STAGE_A(1, 1, 1); STAGE_B(1, 0, 1); STAGE_B(1, 1, 1);
    asm volatile("s_waitcnt vmcnt(8)" ::: "memory");
  } else {
    asm volatile("s_waitcnt vmcnt(0)" ::: "memory");
  }
  SCHED0;
  __builtin_amdgcn_s_barrier();
  SCHED0;

  for (int T = 0; T < nt; ++T){
    const int cb = T & 1;
    const unsigned short* Ab = As + cb * GTILE;
    const unsigned short* Bb = Bs + cb * GTILE;

    // ================= phase 0 =================
    #pragma unroll
    for (int m = 0; m < 4; ++m){
      af[m][0] = *(const short8*)(Ab + arow + m * 1024 + ks0);
      af[m][1] = *(const short8*)(Ab + arow + m * 1024 + ks1);
    }
    #pragma unroll
    for (int n = 0; n < 2; ++n){
      bfr[n][0] = *(const short8*)(Bb + brow + n * 1024 + ks0);
      bfr[n][1] = *(const short8*)(Bb + brow + n * 1024 + ks1);
    }
    SCHED0; __builtin_amdgcn_s_barrier(); SCHED0;
    __builtin_amdgcn_s_setprio(1);
    #pragma unroll
    for (int m = 0; m < 4; ++m)
      #pragma unroll
      for (int n = 0; n < 2; ++n){
        acc[m][n] = __builtin_amdgcn_mfma_f32_16x16x32_bf16(af[m][0], bfr[n][0], acc[m][n], 0, 0, 0);
        acc[m][n] = __builtin_amdgcn_mfma_f32_16x16x32_bf16(af[m][1], bfr[n][1], acc[m][n], 0, 0, 0);
      }
    __builtin_amdgcn_s_setprio(0);
    SCHED0; __builtin_amdgcn_s_barrier(); SCHED0;

    // ================= phase 1 =================
    #pragma unroll
    for (int m = 0; m < 4; ++m){
      af[4+m][0] = *(const short8*)(Ab + arow + (4+m) * 1024 + ks0);
      af[4+m][1] = *(const short8*)(Ab + arow + (4+m) * 1024 + ks1);
    }
    #pragma unroll
    for (int n = 0; n < 2; ++n){
      bfr[2+n][0] = *(const short8*)(Bb + brow + (2+n) * 1024 + ks0);
      bfr[2+n][1] = *(const short8*)(Bb + brow + (2+n) * 1024 + ks1);
    }
    SCHED0; __builtin_amdgcn_s_barrier(); SCHED0;
    __builtin_amdgcn_s_setprio(1);
    #pragma unroll
    for (int m = 0; m < 4; ++m)
      #pragma unroll
      for (int n = 0; n < 2; ++n){
        acc[m][2+n] = __builtin_amdgcn_mfma_f32_16x16x32_bf16(af[m][0], bfr[2+n][0], acc[m][2+n], 0, 0, 0);
        acc[m][2+n] = __builtin_amdgcn_mfma_f32_16x16x32_bf16(af[m][1], bfr[2+n][1], acc[m][2+n], 0, 0, 0);
      }
    __builtin_amdgcn_s_setprio(0);
    SCHED0; __builtin_amdgcn_s_barrier(); SCHED0;

    // ================= phase 2 =================
    // all reads of this buffer were issued before the phase-1 end barrier -> safe to restage
    if (T + 2 < nt){ STAGE_A(cb, 0, T + 2); STAGE_A(cb, 1, T + 2); }
    SCHED0; __builtin_amdgcn_s_barrier(); SCHED0;
    __builtin_amdgcn_s_setprio(1);
    #pragma unroll
    for (int m = 0; m < 4; ++m)
      #pragma unroll
      for (int n = 0; n < 2; ++n){
        acc[4+m][n] = __builtin_amdgcn_mfma_f32_16x16x32_bf16(af[4+m][0], bfr[n][0], acc[4+m][n], 0, 0, 0);
        acc[4+m][n] = __builtin_amdgcn_mfma_f32_16x16x32_bf16(af[4+m][1], bfr[n][1], acc[4+m][n], 0, 0, 0);
      }
    __builtin_amdgcn_s_setprio(0);
    SCHED0; __builtin_amdgcn_s_barrier(); SCHED0;

    // ================= phase 3 =================
    if (T + 2 < nt){
      STAGE_B(cb, 0, T + 2); STAGE_B(cb, 1, T + 2);
      asm volatile("s_waitcnt vmcnt(8)" ::: "memory");   // tile T+1 landed; T+2's 8 stay in flight
    } else {
      asm volatile("s_waitcnt vmcnt(0)" ::: "memory");   // epilogue drain
    }
    SCHED0; __builtin_amdgcn_s_barrier(); SCHED0;
    __builtin_amdgcn_s_setprio(1);
    #pragma unroll
    for (int m = 0; m < 4; ++m)
      #pragma unroll
      for (int n = 0; n < 2; ++n){
        acc[4+m][2+n] = __builtin_amdgcn_mfma_f32_16x16x32_bf16(af[4+m][0], bfr[2+n][0], acc[4+m][2+n], 0, 0, 0);
        acc[4+m][2+n] = __builtin_amdgcn_mfma_f32_16x16x32_bf16(af[4+m][1], bfr[2+n][1], acc[4+m][2+n], 0, 0, 0);
      }
    __builtin_amdgcn_s_setprio(0);
    SCHED0; __builtin_amdgcn_s_barrier(); SCHED0;
  }

#undef STAGE_A
#undef STAGE_B
#undef SCHED0

  #pragma unroll
  for (int mi = 0; mi < 8; ++mi){
    const int row = m0 + wr * 128 + mi * 16 + quad * 4;
    #pragma unroll
    for (int ni = 0; ni < 4; ++ni){
      const int col = n0 + wc * 64 + ni * 16 + l15;
      #pragma unroll
      for (int r = 0; r < 4; ++r)
        C[(size_t)(row + r) * N + col] = acc[mi][ni][r];
    }
  }
}

// ---------------- RoPE + kappa for Q: [B,S,NH,HD] fp32 -> [B,NH,S,HD] bf16 ----------------
__global__ void rope_kappa_q(const float* __restrict__ Qlin, unsigned short* __restrict__ Qk){
  int idx = blockIdx.x * 256 + threadIdx.x;    // B*S*NH*32 = 2^23 threads
  int i = idx & 31;
  int n = (idx >> 5) & (NH_ - 1);
  int s = (idx >> 10) & (S_ - 1);
  int b = idx >> 22;
  float invf = exp2f(-(float)i * (13.287712379549449f / 32.0f));  // 10000^(-i/32)
  float ang = (float)s * invf;
  float c = cosf(ang), sn = sinf(ang);
  size_t in_o = ((size_t)(b * S_ + s) * NH_ + n) * HD_;
  float x1 = Qlin[in_o + i];
  float x2 = Qlin[in_o + i + 32];
  float r1 = x1 * c - x2 * sn;
  float r2 = x2 * c + x1 * sn;
  r1 = r1 > 0.f ? r1 + 1.f : __expf(r1);
  r2 = r2 > 0.f ? r2 + 1.f : __expf(r2);
  size_t o = ((size_t)(b * NH_ + n) * S_ + s) * HD_;
  Qk[o + i] = f2bf(r1);
  Qk[o + i + 32] = f2bf(r2);
}

// ---------------- RoPE + kappa for K (fused KV layout [B,S,1024], K = cols 0..511) ----------------
__global__ void rope_kappa_k(const float* __restrict__ KVlin, unsigned short* __restrict__ Kk){
  int idx = blockIdx.x * 256 + threadIdx.x;    // B*S*NKV*32 = 2^21 threads
  int i = idx & 31;
  int kv = (idx >> 5) & (NKV_ - 1);
  int s = (idx >> 8) & (S_ - 1);
  int b = idx >> 20;
  float invf = exp2f(-(float)i * (13.287712379549449f / 32.0f));
  float ang = (float)s * invf;
  float c = cosf(ang), sn = sinf(ang);
  size_t in_o = (size_t)(b * S_ + s) * 1024 + kv * HD_;
  float x1 = KVlin[in_o + i];
  float x2 = KVlin[in_o + i + 32];
  float r1 = x1 * c - x2 * sn;
  float r2 = x2 * c + x1 * sn;
  r1 = r1 > 0.f ? r1 + 1.f : __expf(r1);
  r2 = r2 > 0.f ? r2 + 1.f : __expf(r2);
  size_t o = ((size_t)(b * NKV_ + kv) * S_ + s) * HD_;
  Kk[o + i] = f2bf(r1);
  Kk[o + i + 32] = f2bf(r2);
}

// ---------------- Qg[b,n,d] = mean_s Qk[b,n,s,d]  (split-S, atomics) ----------------
__global__ __launch_bounds__(256) void qg_mean(const unsigned short* __restrict__ Qk,
                                               float* __restrict__ Qg){
  int bn = blockIdx.x, chunk = blockIdx.y;     // 64 x 16
  int tid = threadIdx.x;
  int dgrp = tid & 7, sgrp = tid >> 3;         // 8 d-chunks x 32 s-rows
  const unsigned short* base = Qk + (size_t)bn * S_ * HD_
                             + (size_t)(chunk * 256 + sgrp) * HD_ + dgrp * 8;
  float acc[8] = {};
  #pragma unroll
  for (int i = 0; i < 8; i++){
    short8 v = *(const short8*)(base + (size_t)i * 32 * HD_);
    #pragma unroll
    for (int e = 0; e < 8; e++) acc[e] += bf2f((unsigned short)v[e]);
  }
  __shared__ float red[256][8];
  #pragma unroll
  for (int e = 0; e < 8; e++) red[tid][e] = acc[e];
  __syncthreads();
  if (tid < 64){
    int dg = tid >> 3, e = tid & 7;
    float s = 0.f;
    #pragma unroll
    for (int g = 0; g < 32; g++) s += red[g * 8 + dg][e];
    atomicAdd(&Qg[bn * 64 + tid], s * (1.0f / (float)S_));
  }
}

// ---------------- logits[b,n,s] = dot(Qg[b,n], Kk[b,kv,s]) ----------------
__global__ __launch_bounds__(256) void logits_kernel(const unsigned short* __restrict__ Kk,
                                                     const float* __restrict__ Qg,
                                                     float* __restrict__ logits){
  int bn = blockIdx.x, chunk = blockIdx.y;     // 64 x 16
  int b = bn / NH_, n = bn % NH_, kv = n / GROUPS_;
  int tid = threadIdx.x;
  __shared__ float qg[64];
  if (tid < 64) qg[tid] = Qg[bn * 64 + tid];
  __syncthreads();
  int s = chunk * 256 + tid;
  const unsigned short* row = Kk + ((size_t)(b * NKV_ + kv) * S_ + s) * HD_;
  float acc = 0.f;
  #pragma unroll
  for (int c = 0; c < 8; c++){
    short8 v = *(const short8*)(row + c * 8);
    #pragma unroll
    for (int e = 0; e < 8; e++) acc += qg[c * 8 + e] * bf2f((unsigned short)v[e]);
  }
  logits[(size_t)bn * S_ + s] = acc;
}

// ---------------- softmax * S over logits -> alpha (in place OK) ----------------
__global__ __launch_bounds__(256) void softmax_kernel(const float* __restrict__ logits,
                                                      float* __restrict__ alpha){
  int bn = blockIdx.x;
  int tid = threadIdx.x;
  float l[16];
  float mymax = -1e30f;
  #pragma unroll
  for (int j = 0; j < 16; j++){
    l[j] = logits[(size_t)bn * S_ + j * 256 + tid];
    mymax = fmaxf(mymax, l[j]);
  }
  __shared__ float red[256];
  red[tid] = mymax; __syncthreads();
  for (int st = 128; st > 0; st >>= 1){
    if (tid < st) red[tid] = fmaxf(red[tid], red[tid + st]);
    __syncthreads();
  }
  float gmax = red[0];
  __syncthreads();
  float mysum = 0.f;
  #pragma unroll
  for (int j = 0; j < 16; j++){ l[j] = __expf(l[j] - gmax); mysum += l[j]; }
  red[tid] = mysum; __syncthreads();
  for (int st = 128; st > 0; st >>= 1){
    if (tid < st) red[tid] += red[tid + st];
    __syncthreads();
  }
  float inv = (float)S_ / red[0];
  #pragma unroll
  for (int j = 0; j < 16; j++)
    alpha[(size_t)bn * S_ + j * 256 + tid] = l[j] * inv;
}

// ---------------- outer_sum: per (b,kv,chunk), all 4 GQA heads; V from fused KV cols 512.. ----------------
__global__ __launch_bounds__(256) void outer_sum_kernel(const unsigned short* __restrict__ Kk,
                                                        const float* __restrict__ KVlin,
                                                        const float* __restrict__ alpha,
                                                        float* __restrict__ part){
  int bkv = blockIdx.x, chunk = blockIdx.y;     // 16 x NCH_
  int b = bkv >> 3, kv = bkv & 7;
  int tid = threadIdx.x;
  int d = tid >> 2, fb = (tid & 3) * 16;
  __shared__ float ks[64][64];   // [si][d]
  __shared__ float vs[64][64];   // [si][f]
  __shared__ float as[4][64];    // [h][si]
  float acc[4][16] = {};
  const unsigned short* kb = Kk + (size_t)(b * NKV_ + kv) * S_ * HD_;
  const int SPC = S_ / NCH_;     // 128 s per chunk

  for (int t = 0; t < SPC / 64; t++){
    int ss = chunk * SPC + t * 64;
    #pragma unroll
    for (int j = 0; j < 16; j++){
      int idx = j * 256 + tid;
      int si = idx >> 6, dd = idx & 63;
      ks[si][dd] = bf2f(kb[(size_t)(ss + si) * HD_ + dd]);
      vs[si][dd] = KVlin[(size_t)(b * S_ + ss + si) * 1024 + 512 + kv * HD_ + dd];
    }
    {
      int h = tid >> 6, si = tid & 63;
      as[h][si] = alpha[(size_t)(b * NH_ + kv * GROUPS_ + h) * S_ + ss + si];
    }
    __syncthreads();
    #pragma unroll 4
    for (int si = 0; si < 64; si++){
      float k = ks[si][d];
      float4 v0 = *(const float4*)&vs[si][fb];
      float4 v1 = *(const float4*)&vs[si][fb + 4];
      float4 v2 = *(const float4*)&vs[si][fb + 8];
      float4 v3 = *(const float4*)&vs[si][fb + 12];
      #pragma unroll
      for (int h = 0; h < 4; h++){
        float ak = as[h][si] * k;
        acc[h][0]  += ak * v0.x; acc[h][1]  += ak * v0.y; acc[h][2]  += ak * v0.z; acc[h][3]  += ak * v0.w;
        acc[h][4]  += ak * v1.x; acc[h][5]  += ak * v1.y; acc[h][6]  += ak * v1.z; acc[h][7]  += ak * v1.w;
        acc[h][8]  += ak * v2.x; acc[h][9]  += ak * v2.y; acc[h][10] += ak * v2.z; acc[h][11] += ak * v2.w;
        acc[h][12] += ak * v3.x; acc[h][13] += ak * v3.y; acc[h][14] += ak * v3.z; acc[h][15] += ak * v3.w;
      }
    }
    __syncthreads();
  }

  #pragma unroll
  for (int h = 0; h < 4; h++){
    float* pb = part + ((size_t)(chunk * 16 + bkv) * 4 + h) * 4096 + d * 64 + fb;
    #pragma unroll
    for (int j = 0; j < 4; j++)
      *(float4*)&pb[j * 4] = *(float4*)&acc[h][j * 4];
  }
}

// ---------------- reduce partials over NCH_ chunks -> osum[bn][d*64+f] ----------------
__global__ __launch_bounds__(256) void osum_reduce(const float* __restrict__ part,
                                                   float* __restrict__ osum){
  int i = blockIdx.x * 256 + threadIdx.x;   // over 64*4096/4 = 65536 float4
  float4 s = {0.f, 0.f, 0.f, 0.f};
  #pragma unroll 8
  for (int c = 0; c < NCH_; c++){
    float4 v = ((const float4*)part)[(size_t)c * 65536 + i];
    s.x += v.x; s.y += v.y; s.z += v.z; s.w += v.w;
  }
  ((float4*)osum)[i] = s;
}

// ---------------- ctx[b,s,n*64+f] = Xphi[b,s,n,f] * sum_d Qk[b,n,s,d]*osum[b,n,d,f] ----------------
__global__ __launch_bounds__(256) void ctx_kernel(const unsigned short* __restrict__ Qk,
                                                  const float* __restrict__ osum,
                                                  const float* __restrict__ Xphi,
                                                  unsigned short* __restrict__ ctx){
  int bn = blockIdx.x, sc = blockIdx.y;
  int b = bn / NH_, n = bn % NH_;
  int tid = threadIdx.x;
  __shared__ float os[64][65];
  __shared__ float qs[64][65];
  #pragma unroll
  for (int j = 0; j < 16; j++){
    int idx = j * 256 + tid;
    int r = idx >> 6, cix = idx & 63;
    os[r][cix] = osum[(size_t)bn * 4096 + idx];
    qs[r][cix] = bf2f(Qk[((size_t)bn * S_ + sc * 64 + r) * HD_ + cix]);
  }
  __syncthreads();
  int sl = tid >> 2, fb = (tid & 3) * 16;
  float r[16] = {};
  #pragma unroll 8
  for (int d = 0; d < 64; d++){
    float q = qs[sl][d];
    #pragma unroll
    for (int j = 0; j < 16; j++) r[j] += q * os[d][fb + j];
  }
  int s = sc * 64 + sl;
  const float* xp = Xphi + ((size_t)(b * S_ + s) * NH_ + n) * HD_ + fb;
  unsigned short* cp = ctx + (size_t)(b * S_ + s) * HID_ + n * HD_ + fb;
  #pragma unroll
  for (int j = 0; j < 16; j++) cp[j] = f2bf(xp[j] * r[j]);
}

extern "C" void kernel_launch(void* const* d_in, const int* in_sizes, int n_in,
                              void* d_out, int out_size, void* d_ws, size_t ws_size,
                              hipStream_t stream) {
  const float* hs   = (const float*)d_in[0];
  const float* Wq   = (const float*)d_in[1];
  const float* Wk   = (const float*)d_in[2];
  const float* Wv   = (const float*)d_in[3];
  const float* Wphi = (const float*)d_in[4];
  const float* Wo   = (const float*)d_in[5];
  float* out = (float*)d_out;

  char* ws = (char*)d_ws;
  const size_t M = (size_t)B_ * S_;          // 8192
  size_t off = 0;
  auto alloc = [&](size_t bytes){ size_t o = off; off += (bytes + 255) & ~(size_t)255; return o; };

  size_t off_hsb   = alloc(M * HID_ * 2);                 // 32MB bf16
  size_t off_wqt   = alloc((size_t)HID_ * HID_ * 2);      // 8MB
  size_t off_wkvt  = alloc((size_t)HID_ * 1024 * 2);      // 4MB  [Wk^T; Wv^T]
  size_t off_wpt   = alloc((size_t)HID_ * HID_ * 2);      // 8MB
  size_t off_wot   = alloc((size_t)HID_ * HID_ * 2);      // 8MB
  size_t off_qlin  = alloc(M * HID_ * 4);                 // 64MB fp32 (Xphi later; osum partials between)
  size_t off_kvlin = alloc(M * 1024 * 4);                 // 32MB fp32 fused K|V
  size_t off_qk    = alloc(M * HID_ * 2);                 // 32MB bf16 [B,NH,S,D]
  size_t off_kk    = alloc(M * 512 * 2);                  // 8MB  bf16 [B,NKV,S,D]
  size_t off_qg    = alloc(64 * 64 * 4);
  size_t off_alph  = alloc((size_t)B_ * NH_ * S_ * 4);    // 1MB
  size_t off_osum  = alloc((size_t)B_ * NH_ * 4096 * 4);  // 1MB
  size_t off_ctx   = off_kvlin;                           // reuse kvlin region (32MB bf16)
  size_t off_part  = off_qlin;                            // 32MB partials in dead qlin window
  (void)ws_size;

  unsigned short* hsb  = (unsigned short*)(ws + off_hsb);
  unsigned short* wqt  = (unsigned short*)(ws + off_wqt);
  unsigned short* wkvt = (unsigned short*)(ws + off_wkvt);
  unsigned short* wpt  = (unsigned short*)(ws + off_wpt);
  unsigned short* wot  = (unsigned short*)(ws + off_wot);
  float* qlin  = (float*)(ws + off_qlin);
  float* kvlin = (float*)(ws + off_kvlin);
  unsigned short* qk = (unsigned short*)(ws + off_qk);
  unsigned short* kk = (unsigned short*)(ws + off_kk);
  float* qg   = (float*)(ws + off_qg);
  float* alph = (float*)(ws + off_alph);
  float* osum = (float*)(ws + off_osum);
  float* part = (float*)(ws + off_part);
  unsigned short* ctx = (unsigned short*)(ws + off_ctx);

  // 1. hs -> bf16
  conv_bf16<<<(int)(M * HID_ / 4 / 256), 256, 0, stream>>>(hs, hsb, (int)(M * HID_ / 4));
  // 2. weight transposes (W[K,N] -> Wt[N,K] bf16); Wk/Wv concatenated
  transpose_to_bf16<<<dim3(HID_/32, HID_/32), dim3(32,8), 0, stream>>>(Wq, wqt, HID_, HID_);
  transpose_to_bf16<<<dim3(512/32,  HID_/32), dim3(32,8), 0, stream>>>(Wk, wkvt, HID_, 512);
  transpose_to_bf16<<<dim3(512/32,  HID_/32), dim3(32,8), 0, stream>>>(Wv, wkvt + (size_t)512 * HID_, HID_, 512);
  transpose_to_bf16<<<dim3(HID_/32, HID_/32), dim3(32,8), 0, stream>>>(Wphi, wpt, HID_, HID_);
  transpose_to_bf16<<<dim3(HID_/32, HID_/32), dim3(32,8), 0, stream>>>(Wo, wot, HID_, HID_);
  // 3-4. Q projection + fused KV projection (256x256-tile 8-phase GEMM)
  gemm256<<<dim3(HID_/256, M/256), 512, 0, stream>>>(hsb, wqt, qlin, (int)M, HID_, HID_);
  gemm256<<<dim3(1024/256, M/256), 512, 0, stream>>>(hsb, wkvt, kvlin, (int)M, 1024, HID_);
  // 5-6. RoPE + kappa (+ layout to [B,H,S,D])
  rope_kappa_q<<<(int)(M * NH_ * 32 / 256), 256, 0, stream>>>(qlin, qk);
  rope_kappa_k<<<(int)(M * NKV_ * 32 / 256), 256, 0, stream>>>(kvlin, kk);
  // 7. global query (split-S + atomics)
  hipMemsetAsync(qg, 0, 64 * 64 * 4, stream);
  qg_mean<<<dim3(B_ * NH_, S_ / 256), 256, 0, stream>>>(qk, qg);
  // 8. logits + softmax * S
  logits_kernel<<<dim3(B_ * NH_, S_ / 256), 256, 0, stream>>>(kk, qg, alph);
  softmax_kernel<<<B_ * NH_, 256, 0, stream>>>(alph, alph);
  // 9. outer_sum (GQA-grouped, atomic-free partials into dead qlin region) + reduce
  outer_sum_kernel<<<dim3(B_ * NKV_, NCH_), 256, 0, stream>>>(kk, kvlin, alph, part);
  osum_reduce<<<256, 256, 0, stream>>>(part, osum);
  // 10. Xphi projection (reuses qlin region — partials dead after reduce)
  gemm256<<<dim3(HID_/256, M/256), 512, 0, stream>>>(hsb, wpt, qlin, (int)M, HID_, HID_);
  // 11. ctx = Xphi * (Qk @ osum)  -> bf16 (reuses kvlin region)
  ctx_kernel<<<dim3(B_ * NH_, S_ / 64), 256, 0, stream>>>(qk, osum, qlin, ctx);
  // 12. out = ctx @ Wo
  gemm256<<<dim3(HID_/256, M/256), 512, 0, stream>>>(ctx, wot, out, (int)M, HID_, HID_);
}

// Round 2
// 566.990 us; speedup vs baseline: 1.2989x; 1.1146x over previous
//
#include <hip/hip_runtime.h>
#include <hip/hip_bf16.h>

#define B_ 2
#define S_ 4096
#define HID_ 2048
#define NH_ 32
#define NKV_ 8
#define HD_ 64
#define GROUPS_ 4
#define NCH_ 32   // outer_sum S-chunks

typedef short short8 __attribute__((ext_vector_type(8)));
typedef float floatx4 __attribute__((ext_vector_type(4)));

__device__ __forceinline__ float bf2f(unsigned short u){
  union { unsigned int i; float f; } v; v.i = ((unsigned int)u) << 16; return v.f;
}
__device__ __forceinline__ unsigned short f2bf(float f){
  union { float f; unsigned int i; } v; v.f = f;
  unsigned int i = v.i;
  unsigned int r = (i + 0x7fffu + ((i >> 16) & 1u)) >> 16;  // RNE
  return (unsigned short)r;
}

// async global->LDS, 16B per lane, LDS dest = wave-uniform base + lane*16
__device__ __forceinline__ void async_copy16(unsigned short* lds, const unsigned short* g){
  __builtin_amdgcn_global_load_lds((const __attribute__((address_space(1))) void*)g,
                                   (__attribute__((address_space(3))) void*)lds,
                                   16, 0, 0);
}

// ---------------- fp32 -> bf16 bulk convert (hidden_states) ----------------
__global__ void conv_bf16(const float* __restrict__ x, unsigned short* __restrict__ y, int n4){
  int i = blockIdx.x * 256 + threadIdx.x;
  if (i < n4){
    float4 v = ((const float4*)x)[i];
    ushort4 o;
    o.x = f2bf(v.x); o.y = f2bf(v.y); o.z = f2bf(v.z); o.w = f2bf(v.w);
    ((ushort4*)y)[i] = o;
  }
}

// ---------------- W[K,N] fp32 -> Wt[N,K] bf16 (tiled transpose) ----------------
__global__ void transpose_to_bf16(const float* __restrict__ W, unsigned short* __restrict__ Wt,
                                  int K, int N){
  __shared__ float tile[32][33];
  int n0 = blockIdx.x * 32, k0 = blockIdx.y * 32;
  int tx = threadIdx.x, ty = threadIdx.y;   // 32 x 8
  #pragma unroll
  for (int j = 0; j < 4; j++)
    tile[ty + j*8][tx] = W[(size_t)(k0 + ty + j*8) * N + n0 + tx];
  __syncthreads();
  #pragma unroll
  for (int j = 0; j < 4; j++)
    Wt[(size_t)(n0 + ty + j*8) * K + k0 + tx] = f2bf(tile[tx][ty + j*8]);
}

// ---------------- 256x256-tile 8-phase GEMM: C[M,N] fp32 = A[M,K] bf16 @ Bt[N,K]^T ----------------
#define GTILE 16384   // 256*64 bf16 elements per operand per buffer

__global__ __launch_bounds__(512, 2) void gemm256(
    const unsigned short* __restrict__ A, const unsigned short* __restrict__ Bt,
    float* __restrict__ C, int M, int N, int K)
{
  __shared__ __align__(16) unsigned short As[2 * GTILE];
  __shared__ __align__(16) unsigned short Bs[2 * GTILE];

  const int tid = threadIdx.x;
  const int w = tid >> 6, lane = tid & 63;
  const int wr = w >> 2, wc = w & 3;
  const int l15 = lane & 15, quad = lane >> 4;

  // bijective XCD-aware swizzle (nwg % 8 == 0 for all shapes here)
  const int nbx = N >> 8;
  int flat = blockIdx.y * nbx + blockIdx.x;
  int nwg  = nbx * (M >> 8);
  int cpx  = nwg >> 3;
  int swz  = (flat & 7) * cpx + (flat >> 3);
  int bx = swz % nbx, by = swz / nbx;
  const int m0 = by << 8, n0 = bx << 8;

  // ---- staging addressing (per wave-call: 64 lanes x 16B = 512 shorts linear in LDS) ----
  const int srow = (w << 3) + (lane >> 3);          // row 0..63 within a 64-row call
  const int scc  = (lane & 7) ^ (lane >> 3);        // swizzled 16B chunk within 128B row
  const unsigned short* gA = A  + (size_t)(m0 + srow) * K + scc * 8;
  const unsigned short* gB = Bt + (size_t)(n0 + srow) * K + scc * 8;
  const size_t rs64  = (size_t)64  * K;             // second-call row offset
  const size_t rs128 = (size_t)128 * K;             // half-tile row offset
  unsigned short* lA0 = As + (w << 9);
  unsigned short* lB0 = Bs + (w << 9);

#define STAGE_A(bsel, h, t) do { \
    unsigned short* _d = lA0 + (bsel) * GTILE + (h) * 8192; \
    const unsigned short* _g = gA + (size_t)(h) * rs128 + (size_t)(t) * 64; \
    async_copy16(_d, _g); \
    async_copy16(_d + 4096, _g + rs64); \
  } while (0)
#define STAGE_B(bsel, h, t) do { \
    unsigned short* _d = lB0 + (bsel) * GTILE + (h) * 8192; \
    const unsigned short* _g = gB + (size_t)(h) * rs128 + (size_t)(t) * 64; \
    async_copy16(_d, _g); \
    async_copy16(_d + 4096, _g + rs64); \
  } while (0)
#define SCHED0 __builtin_amdgcn_sched_barrier(0)

  // ---- fragment read offsets (shorts): row*64 + ((kchunk ^ (row&7))<<3); row&7 == lane&7 ----
  const int ks0  = ((quad     ^ (lane & 7)) << 3);
  const int ks1  = (((4+quad) ^ (lane & 7)) << 3);
  const int arow = (wr * 128 + l15) * 64;
  const int brow = (wc * 64  + l15) * 64;

  floatx4 acc[8][4] = {};
  short8 af[8][2], bfr[4][2];

  const int nt = K >> 6;

  // ---- prologue: stage tile0 (buf0) and tile1 (buf1); allow tile1's 8 loads in flight ----
  STAGE_A(0, 0, 0); STAGE_A(0, 1, 0); STAGE_B(0, 0, 0); STAGE_B(0, 1, 0);
  if (nt > 1){
    STAGE_A(1, 0, 1); STAGE_A(1, 1, 1); STAGE_B(1, 0, 1); STAGE_B(1, 1, 1);
    asm volatile("s_waitcnt vmcnt(8)" ::: "memory");
  } else {
    asm volatile("s_waitcnt vmcnt(0)" ::: "memory");
  }
  SCHED0;
  __builtin_amdgcn_s_barrier();
  SCHED0;

  for (int T = 0; T < nt; ++T){
    const int cb = T & 1;
    const unsigned short* Ab = As + cb * GTILE;
    const unsigned short* Bb = Bs + cb * GTILE;

    // ================= phase 0 =================
    #pragma unroll
    for (int m = 0; m < 4; ++m){
      af[m][0] = *(const short8*)(Ab + arow + m * 1024 + ks0);
      af[m][1] = *(const short8*)(Ab + arow + m * 1024 + ks1);
    }
    #pragma unroll
    for (int n = 0; n < 2; ++n){
      bfr[n][0] = *(const short8*)(Bb + brow + n * 1024 + ks0);
      bfr[n][1] = *(const short8*)(Bb + brow + n * 1024 + ks1);
    }
    SCHED0; __builtin_amdgcn_s_barrier(); SCHED0;
    __builtin_amdgcn_s_setprio(1);
    #pragma unroll
    for (int m = 0; m < 4; ++m)
      #pragma unroll
      for (int n = 0; n < 2; ++n){
        acc[m][n] = __builtin_amdgcn_mfma_f32_16x16x32_bf16(af[m][0], bfr[n][0], acc[m][n], 0, 0, 0);
        acc[m][n] = __builtin_amdgcn_mfma_f32_16x16x32_bf16(af[m][1], bfr[n][1], acc[m][n], 0, 0, 0);
      }
    __builtin_amdgcn_s_setprio(0);
    SCHED0; __builtin_amdgcn_s_barrier(); SCHED0;

    // ================= phase 1 =================
    #pragma unroll
    for (int m = 0; m < 4; ++m){
      af[4+m][0] = *(const short8*)(Ab + arow + (4+m) * 1024 + ks0);
      af[4+m][1] = *(const short8*)(Ab + arow + (4+m) * 1024 + ks1);
    }
    #pragma unroll
    for (int n = 0; n < 2; ++n){
      bfr[2+n][0] = *(const short8*)(Bb + brow + (2+n) * 1024 + ks0);
      bfr[2+n][1] = *(const short8*)(Bb + brow + (2+n) * 1024 + ks1);
    }
    SCHED0; __builtin_amdgcn_s_barrier(); SCHED0;
    __builtin_amdgcn_s_setprio(1);
    #pragma unroll
    for (int m = 0; m < 4; ++m)
      #pragma unroll
      for (int n = 0; n < 2; ++n){
        acc[m][2+n] = __builtin_amdgcn_mfma_f32_16x16x32_bf16(af[m][0], bfr[2+n][0], acc[m][2+n], 0, 0, 0);
        acc[m][2+n] = __builtin_amdgcn_mfma_f32_16x16x32_bf16(af[m][1], bfr[2+n][1], acc[m][2+n], 0, 0, 0);
      }
    __builtin_amdgcn_s_setprio(0);
    SCHED0; __builtin_amdgcn_s_barrier(); SCHED0;

    // ================= phase 2 =================
    if (T + 2 < nt){ STAGE_A(cb, 0, T + 2); STAGE_A(cb, 1, T + 2); }
    SCHED0; __builtin_amdgcn_s_barrier(); SCHED0;
    __builtin_amdgcn_s_setprio(1);
    #pragma unroll
    for (int m = 0; m < 4; ++m)
      #pragma unroll
      for (int n = 0; n < 2; ++n){
        acc[4+m][n] = __builtin_amdgcn_mfma_f32_16x16x32_bf16(af[4+m][0], bfr[n][0], acc[4+m][n], 0, 0, 0);
        acc[4+m][n] = __builtin_amdgcn_mfma_f32_16x16x32_bf16(af[4+m][1], bfr[n][1], acc[4+m][n], 0, 0, 0);
      }
    __builtin_amdgcn_s_setprio(0);
    SCHED0; __builtin_amdgcn_s_barrier(); SCHED0;

    // ================= phase 3 =================
    if (T + 2 < nt){
      STAGE_B(cb, 0, T + 2); STAGE_B(cb, 1, T + 2);
      asm volatile("s_waitcnt vmcnt(8)" ::: "memory");   // tile T+1 landed; T+2's 8 stay in flight
    } else {
      asm volatile("s_waitcnt vmcnt(0)" ::: "memory");   // epilogue drain
    }
    SCHED0; __builtin_amdgcn_s_barrier(); SCHED0;
    __builtin_amdgcn_s_setprio(1);
    #pragma unroll
    for (int m = 0; m < 4; ++m)
      #pragma unroll
      for (int n = 0; n < 2; ++n){
        acc[4+m][2+n] = __builtin_amdgcn_mfma_f32_16x16x32_bf16(af[4+m][0], bfr[2+n][0], acc[4+m][2+n], 0, 0, 0);
        acc[4+m][2+n] = __builtin_amdgcn_mfma_f32_16x16x32_bf16(af[4+m][1], bfr[2+n][1], acc[4+m][2+n], 0, 0, 0);
      }
    __builtin_amdgcn_s_setprio(0);
    SCHED0; __builtin_amdgcn_s_barrier(); SCHED0;
  }

#undef STAGE_A
#undef STAGE_B
#undef SCHED0

  #pragma unroll
  for (int mi = 0; mi < 8; ++mi){
    const int row = m0 + wr * 128 + mi * 16 + quad * 4;
    #pragma unroll
    for (int ni = 0; ni < 4; ++ni){
      const int col = n0 + wc * 64 + ni * 16 + l15;
      #pragma unroll
      for (int r = 0; r < 4; ++r)
        C[(size_t)(row + r) * N + col] = acc[mi][ni][r];
    }
  }
}

// ---------------- RoPE + kappa for Q: [B,S,NH,HD] fp32 -> [B,NH,S,HD] bf16 ----------------
__global__ void rope_kappa_q(const float* __restrict__ Qlin, unsigned short* __restrict__ Qk){
  int idx = blockIdx.x * 256 + threadIdx.x;    // B*S*NH*32 = 2^23 threads
  int i = idx & 31;
  int n = (idx >> 5) & (NH_ - 1);
  int s = (idx >> 10) & (S_ - 1);
  int b = idx >> 22;
  float invf = exp2f(-(float)i * (13.287712379549449f / 32.0f));  // 10000^(-i/32)
  float ang = (float)s * invf;
  float c = cosf(ang), sn = sinf(ang);
  size_t in_o = ((size_t)(b * S_ + s) * NH_ + n) * HD_;
  float x1 = Qlin[in_o + i];
  float x2 = Qlin[in_o + i + 32];
  float r1 = x1 * c - x2 * sn;
  float r2 = x2 * c + x1 * sn;
  r1 = r1 > 0.f ? r1 + 1.f : __expf(r1);
  r2 = r2 > 0.f ? r2 + 1.f : __expf(r2);
  size_t o = ((size_t)(b * NH_ + n) * S_ + s) * HD_;
  Qk[o + i] = f2bf(r1);
  Qk[o + i + 32] = f2bf(r2);
}

// ---------------- RoPE + kappa for K (fused KV layout [B,S,1024], K = cols 0..511) ----------------
__global__ void rope_kappa_k(const float* __restrict__ KVlin, unsigned short* __restrict__ Kk){
  int idx = blockIdx.x * 256 + threadIdx.x;    // B*S*NKV*32 = 2^21 threads
  int i = idx & 31;
  int kv = (idx >> 5) & (NKV_ - 1);
  int s = (idx >> 8) & (S_ - 1);
  int b = idx >> 20;
  float invf = exp2f(-(float)i * (13.287712379549449f / 32.0f));
  float ang = (float)s * invf;
  float c = cosf(ang), sn = sinf(ang);
  size_t in_o = (size_t)(b * S_ + s) * 1024 + kv * HD_;
  float x1 = KVlin[in_o + i];
  float x2 = KVlin[in_o + i + 32];
  float r1 = x1 * c - x2 * sn;
  float r2 = x2 * c + x1 * sn;
  r1 = r1 > 0.f ? r1 + 1.f : __expf(r1);
  r2 = r2 > 0.f ? r2 + 1.f : __expf(r2);
  size_t o = ((size_t)(b * NKV_ + kv) * S_ + s) * HD_;
  Kk[o + i] = f2bf(r1);
  Kk[o + i + 32] = f2bf(r2);
}

// ---------------- Qg[b,n,d] = mean_s Qk[b,n,s,d]  (split-S, atomics) ----------------
__global__ __launch_bounds__(256) void qg_mean(const unsigned short* __restrict__ Qk,
                                               float* __restrict__ Qg){
  int bn = blockIdx.x, chunk = blockIdx.y;     // 64 x 16
  int tid = threadIdx.x;
  int dgrp = tid & 7, sgrp = tid >> 3;         // 8 d-chunks x 32 s-rows
  const unsigned short* base = Qk + (size_t)bn * S_ * HD_
                             + (size_t)(chunk * 256 + sgrp) * HD_ + dgrp * 8;
  float acc[8] = {};
  #pragma unroll
  for (int i = 0; i < 8; i++){
    short8 v = *(const short8*)(base + (size_t)i * 32 * HD_);
    #pragma unroll
    for (int e = 0; e < 8; e++) acc[e] += bf2f((unsigned short)v[e]);
  }
  __shared__ float red[256][8];
  #pragma unroll
  for (int e = 0; e < 8; e++) red[tid][e] = acc[e];
  __syncthreads();
  if (tid < 64){
    int dg = tid >> 3, e = tid & 7;
    float s = 0.f;
    #pragma unroll
    for (int g = 0; g < 32; g++) s += red[g * 8 + dg][e];
    atomicAdd(&Qg[bn * 64 + tid], s * (1.0f / (float)S_));
  }
}

// ---------------- logits[b,n,s] = dot(Qg[b,n], Kk[b,kv,s]) ----------------
__global__ __launch_bounds__(256) void logits_kernel(const unsigned short* __restrict__ Kk,
                                                     const float* __restrict__ Qg,
                                                     float* __restrict__ logits){
  int bn = blockIdx.x, chunk = blockIdx.y;     // 64 x 16
  int b = bn / NH_, n = bn % NH_, kv = n / GROUPS_;
  int tid = threadIdx.x;
  __shared__ float qg[64];
  if (tid < 64) qg[tid] = Qg[bn * 64 + tid];
  __syncthreads();
  int s = chunk * 256 + tid;
  const unsigned short* row = Kk + ((size_t)(b * NKV_ + kv) * S_ + s) * HD_;
  float acc = 0.f;
  #pragma unroll
  for (int c = 0; c < 8; c++){
    short8 v = *(const short8*)(row + c * 8);
    #pragma unroll
    for (int e = 0; e < 8; e++) acc += qg[c * 8 + e] * bf2f((unsigned short)v[e]);
  }
  logits[(size_t)bn * S_ + s] = acc;
}

// ---------------- softmax * S over logits -> alpha (in place OK) ----------------
__global__ __launch_bounds__(256) void softmax_kernel(const float* __restrict__ logits,
                                                      float* __restrict__ alpha){
  int bn = blockIdx.x;
  int tid = threadIdx.x;
  float l[16];
  float mymax = -1e30f;
  #pragma unroll
  for (int j = 0; j < 16; j++){
    l[j] = logits[(size_t)bn * S_ + j * 256 + tid];
    mymax = fmaxf(mymax, l[j]);
  }
  __shared__ float red[256];
  red[tid] = mymax; __syncthreads();
  for (int st = 128; st > 0; st >>= 1){
    if (tid < st) red[tid] = fmaxf(red[tid], red[tid + st]);
    __syncthreads();
  }
  float gmax = red[0];
  __syncthreads();
  float mysum = 0.f;
  #pragma unroll
  for (int j = 0; j < 16; j++){ l[j] = __expf(l[j] - gmax); mysum += l[j]; }
  red[tid] = mysum; __syncthreads();
  for (int st = 128; st > 0; st >>= 1){
    if (tid < st) red[tid] += red[tid + st];
    __syncthreads();
  }
  float inv = (float)S_ / red[0];
  #pragma unroll
  for (int j = 0; j < 16; j++)
    alpha[(size_t)bn * S_ + j * 256 + tid] = l[j] * inv;
}

// ---------------- outer_sum: per (b,kv,chunk), all 4 GQA heads; V from fused KV cols 512.. ----------------
__global__ __launch_bounds__(256) void outer_sum_kernel(const unsigned short* __restrict__ Kk,
                                                        const float* __restrict__ KVlin,
                                                        const float* __restrict__ alpha,
                                                        float* __restrict__ part){
  int bkv = blockIdx.x, chunk = blockIdx.y;     // 16 x NCH_
  int b = bkv >> 3, kv = bkv & 7;
  int tid = threadIdx.x;
  int d = tid >> 2, fb = (tid & 3) * 16;
  __shared__ float ks[64][64];   // [si][d]
  __shared__ float vs[64][64];   // [si][f]
  __shared__ float as[4][64];    // [h][si]
  float acc[4][16] = {};
  const unsigned short* kb = Kk + (size_t)(b * NKV_ + kv) * S_ * HD_;
  const int SPC = S_ / NCH_;     // 128 s per chunk

  for (int t = 0; t < SPC / 64; t++){
    int ss = chunk * SPC + t * 64;
    #pragma unroll
    for (int j = 0; j < 16; j++){
      int idx = j * 256 + tid;
      int si = idx >> 6, dd = idx & 63;
      ks[si][dd] = bf2f(kb[(size_t)(ss + si) * HD_ + dd]);
      vs[si][dd] = KVlin[(size_t)(b * S_ + ss + si) * 1024 + 512 + kv * HD_ + dd];
    }
    {
      int h = tid >> 6, si = tid & 63;
      as[h][si] = alpha[(size_t)(b * NH_ + kv * GROUPS_ + h) * S_ + ss + si];
    }
    __syncthreads();
    #pragma unroll 4
    for (int si = 0; si < 64; si++){
      float k = ks[si][d];
      float4 v0 = *(const float4*)&vs[si][fb];
      float4 v1 = *(const float4*)&vs[si][fb + 4];
      float4 v2 = *(const float4*)&vs[si][fb + 8];
      float4 v3 = *(const float4*)&vs[si][fb + 12];
      #pragma unroll
      for (int h = 0; h < 4; h++){
        float ak = as[h][si] * k;
        acc[h][0]  += ak * v0.x; acc[h][1]  += ak * v0.y; acc[h][2]  += ak * v0.z; acc[h][3]  += ak * v0.w;
        acc[h][4]  += ak * v1.x; acc[h][5]  += ak * v1.y; acc[h][6]  += ak * v1.z; acc[h][7]  += ak * v1.w;
        acc[h][8]  += ak * v2.x; acc[h][9]  += ak * v2.y; acc[h][10] += ak * v2.z; acc[h][11] += ak * v2.w;
        acc[h][12] += ak * v3.x; acc[h][13] += ak * v3.y; acc[h][14] += ak * v3.z; acc[h][15] += ak * v3.w;
      }
    }
    __syncthreads();
  }

  #pragma unroll
  for (int h = 0; h < 4; h++){
    float* pb = part + ((size_t)(chunk * 16 + bkv) * 4 + h) * 4096 + d * 64 + fb;
    #pragma unroll
    for (int j = 0; j < 4; j++)
      *(float4*)&pb[j * 4] = *(float4*)&acc[h][j * 4];
  }
}

// ---------------- reduce partials over NCH_ chunks -> transposed split-bf16 osum ----------------
// osumb layout: [bn][plane][f][d] bf16, plane 0 = hi, plane 1 = lo (x - hi).
// hi+lo reproduces fp32 osum to ~2^-17 relative -> no precision loss vs fp32 path.
__global__ __launch_bounds__(256) void osum_reduce_t(const float* __restrict__ part,
                                                     unsigned short* __restrict__ osumb){
  int bn = blockIdx.x;            // 64
  int tid = threadIdx.x;
  __shared__ float os[64][65];
  const float4* p4 = (const float4*)part;
  #pragma unroll
  for (int r = 0; r < 4; r++){
    int idx4 = r * 256 + tid;     // float4 index within this bn's 1024
    float4 s = {0.f, 0.f, 0.f, 0.f};
    #pragma unroll 8
    for (int c = 0; c < NCH_; c++){
      float4 v = p4[(size_t)c * 65536 + bn * 1024 + idx4];
      s.x += v.x; s.y += v.y; s.z += v.z; s.w += v.w;
    }
    int d = idx4 >> 4;            // (idx4*4)/64
    int f0 = (idx4 & 15) * 4;
    os[d][f0] = s.x; os[d][f0+1] = s.y; os[d][f0+2] = s.z; os[d][f0+3] = s.w;
  }
  __syncthreads();
  int f = tid >> 2, d0 = (tid & 3) * 16;
  unsigned short hi[16], lo[16];
  #pragma unroll
  for (int j = 0; j < 16; j++){
    float x = os[d0 + j][f];
    unsigned short h = f2bf(x);
    hi[j] = h;
    lo[j] = f2bf(x - bf2f(h));
  }
  unsigned short* oh = osumb + ((size_t)bn * 2) * 4096 + (size_t)f * 64 + d0;
  unsigned short* ol = oh + 4096;
  *(short8*)(oh)     = *(const short8*)(hi);
  *(short8*)(oh + 8) = *(const short8*)(hi + 8);
  *(short8*)(ol)     = *(const short8*)(lo);
  *(short8*)(ol + 8) = *(const short8*)(lo + 8);
}

// ---------------- ctx via MFMA: R = Qk @ osum (hi+lo), ctx = bf16(Xphi * R) ----------------
// Per block: one bn, 256 s-rows. 4 waves x (4 m-frags x 4 n-frags) mfma_16x16x32_bf16.
// No LDS. A-frags straight from global Qk (region fully consumed -> read-once);
// B-frags from osumb (16KB/bn, L2-resident across the 16 s-chunks).
__global__ __launch_bounds__(256) void ctx_mfma(const unsigned short* __restrict__ Qk,
                                                const unsigned short* __restrict__ osumb,
                                                const float* __restrict__ Xphi,
                                                unsigned short* __restrict__ ctx){
  int bn = blockIdx.x, sc = blockIdx.y;   // 64 x 16
  int b = bn >> 5, n = bn & 31;
  int tid = threadIdx.x;
  int w = tid >> 6, lane = tid & 63;
  int l15 = lane & 15, quad = lane >> 4;

  const unsigned short* obase = osumb + ((size_t)bn * 2) * 4096;
  short8 bh[4][2], bl[4][2];
  #pragma unroll
  for (int nf = 0; nf < 4; nf++){
    int f = nf * 16 + l15;
    #pragma unroll
    for (int kh = 0; kh < 2; kh++){
      bh[nf][kh] = *(const short8*)(obase + (size_t)f * 64 + kh * 32 + quad * 8);
      bl[nf][kh] = *(const short8*)(obase + 4096 + (size_t)f * 64 + kh * 32 + quad * 8);
    }
  }

  int s0 = sc * 256 + w * 64;
  const unsigned short* qbase = Qk + ((size_t)bn * S_ + s0) * HD_;
  floatx4 acc[4][4] = {};
  #pragma unroll
  for (int m = 0; m < 4; m++){
    short8 a0 = *(const short8*)(qbase + (size_t)(m * 16 + l15) * HD_ + quad * 8);
    short8 a1 = *(const short8*)(qbase + (size_t)(m * 16 + l15) * HD_ + 32 + quad * 8);
    #pragma unroll
    for (int nf = 0; nf < 4; nf++){
      acc[m][nf] = __builtin_amdgcn_mfma_f32_16x16x32_bf16(a0, bh[nf][0], acc[m][nf], 0, 0, 0);
      acc[m][nf] = __builtin_amdgcn_mfma_f32_16x16x32_bf16(a1, bh[nf][1], acc[m][nf], 0, 0, 0);
      acc[m][nf] = __builtin_amdgcn_mfma_f32_16x16x32_bf16(a0, bl[nf][0], acc[m][nf], 0, 0, 0);
      acc[m][nf] = __builtin_amdgcn_mfma_f32_16x16x32_bf16(a1, bl[nf][1], acc[m][nf], 0, 0, 0);
    }
  }

  // epilogue: C/D mapping col=l15, row=quad*4+r; multiply by Xphi, store bf16
  #pragma unroll
  for (int m = 0; m < 4; m++){
    #pragma unroll
    for (int r = 0; r < 4; r++){
      int s = s0 + m * 16 + quad * 4 + r;
      const float* xp = Xphi + ((size_t)(b * S_ + s) * NH_ + n) * HD_;
      unsigned short* cp = ctx + (size_t)(b * S_ + s) * HID_ + n * HD_;
      #pragma unroll
      for (int nf = 0; nf < 4; nf++){
        int f = nf * 16 + l15;
        cp[f] = f2bf(xp[f] * acc[m][nf][r]);
      }
    }
  }
}

extern "C" void kernel_launch(void* const* d_in, const int* in_sizes, int n_in,
                              void* d_out, int out_size, void* d_ws, size_t ws_size,
                              hipStream_t stream) {
  const float* hs   = (const float*)d_in[0];
  const float* Wq   = (const float*)d_in[1];
  const float* Wk   = (const float*)d_in[2];
  const float* Wv   = (const float*)d_in[3];
  const float* Wphi = (const float*)d_in[4];
  const float* Wo   = (const float*)d_in[5];
  float* out = (float*)d_out;

  char* ws = (char*)d_ws;
  const size_t M = (size_t)B_ * S_;          // 8192
  size_t off = 0;
  auto alloc = [&](size_t bytes){ size_t o = off; off += (bytes + 255) & ~(size_t)255; return o; };

  size_t off_hsb   = alloc(M * HID_ * 2);                 // 32MB bf16
  size_t off_wqt   = alloc((size_t)HID_ * HID_ * 2);      // 8MB
  size_t off_wkvt  = alloc((size_t)HID_ * 1024 * 2);      // 4MB  [Wk^T; Wv^T]
  size_t off_wpt   = alloc((size_t)HID_ * HID_ * 2);      // 8MB
  size_t off_wot   = alloc((size_t)HID_ * HID_ * 2);      // 8MB
  size_t off_qlin  = alloc(M * HID_ * 4);                 // 64MB fp32 (Xphi later; osum partials between)
  size_t off_kvlin = alloc(M * 1024 * 4);                 // 32MB fp32 fused K|V
  size_t off_qk    = alloc(M * HID_ * 2);                 // 32MB bf16 [B,NH,S,D]
  size_t off_kk    = alloc(M * 512 * 2);                  // 8MB  bf16 [B,NKV,S,D]
  size_t off_qg    = alloc(64 * 64 * 4);
  size_t off_alph  = alloc((size_t)B_ * NH_ * S_ * 4);    // 1MB
  size_t off_osumb = alloc((size_t)64 * 2 * 4096 * 2);    // 1MB split-bf16 osum^T
  size_t off_ctx   = off_kvlin;                           // reuse kvlin region (32MB bf16)
  size_t off_part  = off_qlin;                            // 32MB partials in dead qlin window
  (void)ws_size;

  unsigned short* hsb  = (unsigned short*)(ws + off_hsb);
  unsigned short* wqt  = (unsigned short*)(ws + off_wqt);
  unsigned short* wkvt = (unsigned short*)(ws + off_wkvt);
  unsigned short* wpt  = (unsigned short*)(ws + off_wpt);
  unsigned short* wot  = (unsigned short*)(ws + off_wot);
  float* qlin  = (float*)(ws + off_qlin);
  float* kvlin = (float*)(ws + off_kvlin);
  unsigned short* qk = (unsigned short*)(ws + off_qk);
  unsigned short* kk = (unsigned short*)(ws + off_kk);
  float* qg   = (float*)(ws + off_qg);
  float* alph = (float*)(ws + off_alph);
  unsigned short* osumb = (unsigned short*)(ws + off_osumb);
  float* part = (float*)(ws + off_part);
  unsigned short* ctx = (unsigned short*)(ws + off_ctx);

  // 1. hs -> bf16
  conv_bf16<<<(int)(M * HID_ / 4 / 256), 256, 0, stream>>>(hs, hsb, (int)(M * HID_ / 4));
  // 2. weight transposes (W[K,N] -> Wt[N,K] bf16); Wk/Wv concatenated
  transpose_to_bf16<<<dim3(HID_/32, HID_/32), dim3(32,8), 0, stream>>>(Wq, wqt, HID_, HID_);
  transpose_to_bf16<<<dim3(512/32,  HID_/32), dim3(32,8), 0, stream>>>(Wk, wkvt, HID_, 512);
  transpose_to_bf16<<<dim3(512/32,  HID_/32), dim3(32,8), 0, stream>>>(Wv, wkvt + (size_t)512 * HID_, HID_, 512);
  transpose_to_bf16<<<dim3(HID_/32, HID_/32), dim3(32,8), 0, stream>>>(Wphi, wpt, HID_, HID_);
  transpose_to_bf16<<<dim3(HID_/32, HID_/32), dim3(32,8), 0, stream>>>(Wo, wot, HID_, HID_);
  // 3-4. Q projection + fused KV projection (256x256-tile 8-phase GEMM)
  gemm256<<<dim3(HID_/256, M/256), 512, 0, stream>>>(hsb, wqt, qlin, (int)M, HID_, HID_);
  gemm256<<<dim3(1024/256, M/256), 512, 0, stream>>>(hsb, wkvt, kvlin, (int)M, 1024, HID_);
  // 5-6. RoPE + kappa (+ layout to [B,H,S,D])
  rope_kappa_q<<<(int)(M * NH_ * 32 / 256), 256, 0, stream>>>(qlin, qk);
  rope_kappa_k<<<(int)(M * NKV_ * 32 / 256), 256, 0, stream>>>(kvlin, kk);
  // 7. global query (split-S + atomics)
  hipMemsetAsync(qg, 0, 64 * 64 * 4, stream);
  qg_mean<<<dim3(B_ * NH_, S_ / 256), 256, 0, stream>>>(qk, qg);
  // 8. logits + softmax * S
  logits_kernel<<<dim3(B_ * NH_, S_ / 256), 256, 0, stream>>>(kk, qg, alph);
  softmax_kernel<<<B_ * NH_, 256, 0, stream>>>(alph, alph);
  // 9. outer_sum (partials into dead qlin region) + transposed split-bf16 reduce
  outer_sum_kernel<<<dim3(B_ * NKV_, NCH_), 256, 0, stream>>>(kk, kvlin, alph, part);
  osum_reduce_t<<<64, 256, 0, stream>>>(part, osumb);
  // 10. Xphi projection (reuses qlin region — partials dead after reduce)
  gemm256<<<dim3(HID_/256, M/256), 512, 0, stream>>>(hsb, wpt, qlin, (int)M, HID_, HID_);
  // 11. ctx = Xphi * (Qk @ osum)  -> bf16 (MFMA, reuses kvlin region)
  ctx_mfma<<<dim3(B_ * NH_, S_ / 64 / 4), 256, 0, stream>>>(qk, osumb, qlin, ctx);
  // 12. out = ctx @ Wo
  gemm256<<<dim3(HID_/256, M/256), 512, 0, stream>>>(ctx, wot, out, (int)M, HID_, HID_);
}